// Round 1
// baseline (75.436 us; speedup 1.0000x reference)
//
#include <hip/hip_runtime.h>
#include <math.h>

#define NN 8192
#define IN_F 128
#define OUT_F 64
#define NEG_SLOPE 0.01f

// Kernel 1: z = X @ W^T + b ; per-row zi = dot(a1, z_i), zj = dot(a2, z_i);
// e_i = exp(lrelu(zi)), d_i = exp(lrelu(zi+zj)).
// Block = 256 threads = 4 waves; each wave computes one row of z (64 feats).
__global__ __launch_bounds__(256) void k1_linear(
    const float* __restrict__ X, const float* __restrict__ W,
    const float* __restrict__ b, const float* __restrict__ a1,
    const float* __restrict__ a2, float* __restrict__ z,
    float* __restrict__ ev, float* __restrict__ dv)
{
    __shared__ float Wl[OUT_F * 129];   // +1 pad per row -> conflict-free
    __shared__ float xs[4 * IN_F];
    const int t = threadIdx.x;
    const int blk = blockIdx.x;

    // Stage W [64x128] into LDS (coalesced)
    for (int idx = t; idx < OUT_F * IN_F; idx += 256) {
        int f = idx >> 7, k = idx & 127;
        Wl[f * 129 + k] = W[idx];
    }
    // Stage 4 rows of X
    for (int idx = t; idx < 4 * IN_F; idx += 256) {
        xs[idx] = X[(size_t)blk * (4 * IN_F) + idx];
    }
    __syncthreads();

    const int r = t >> 6;      // wave id = row within block
    const int f = t & 63;      // lane = output feature
    float acc = 0.f;
#pragma unroll 8
    for (int k = 0; k < IN_F; ++k)
        acc = fmaf(xs[r * IN_F + k], Wl[f * 129 + k], acc);
    const float zval = acc + b[f];
    z[blk * 256 + t] = zval;   // == z[(blk*4+r)*64 + f], coalesced

    float p1 = a1[f] * zval;
    float p2 = a2[f] * zval;
#pragma unroll
    for (int off = 32; off > 0; off >>= 1) {
        p1 += __shfl_down(p1, off, 64);
        p2 += __shfl_down(p2, off, 64);
    }
    if (f == 0) {
        const int i = blk * 4 + r;
        const float zi = p1, zj = p2;
        const float s1 = zi;
        const float s2 = zi + zj;
        const float l1 = s1 > 0.f ? s1 : NEG_SLOPE * s1;
        const float l2 = s2 > 0.f ? s2 : NEG_SLOPE * s2;
        ev[i] = expf(l1);
        dv[i] = expf(l2);
    }
}

// Kernel 2: one block per row i. Stream A[i,:] (32 KB, float4 coalesced),
// compute deg_i = sum(A[i,:]) and sumNbr_i = sum_{A[i,j]!=0} z[j,:] via an
// LDS nonzero-index list + cooperative gather. Then
//   S = (deg-1)*e + d ;  out = relu( z_i*(1+(e-d)/S) - (e/S)*sumNbr ).
__global__ __launch_bounds__(256) void k2_row(
    const float* __restrict__ A, const float* __restrict__ z,
    const float* __restrict__ ev, const float* __restrict__ dv,
    float* __restrict__ out)
{
    __shared__ int   list[1024];
    __shared__ int   cnt;
    __shared__ float accw[4][64];
    __shared__ float degw[4];

    const int i = blockIdx.x;
    const int t = threadIdx.x;
    const int wid = t >> 6, lane = t & 63;
    const float4* __restrict__ Arow =
        reinterpret_cast<const float4*>(A + (size_t)i * NN);

    float accReg = 0.f;     // this thread's partial of sumNbr[lane]
    float degLocal = 0.f;

    // 8 chunks of 1024 columns (256 threads x float4)
    for (int c = 0; c < NN / 1024; ++c) {
        __syncthreads();              // prev chunk's list/cnt fully consumed
        if (t == 0) cnt = 0;
        __syncthreads();

        const float4 a4 = Arow[c * 256 + t];
        degLocal += a4.x + a4.y + a4.z + a4.w;
        const int j0 = c * 1024 + t * 4;
        if (a4.x != 0.f) list[atomicAdd(&cnt, 1)] = j0;
        if (a4.y != 0.f) list[atomicAdd(&cnt, 1)] = j0 + 1;
        if (a4.z != 0.f) list[atomicAdd(&cnt, 1)] = j0 + 2;
        if (a4.w != 0.f) list[atomicAdd(&cnt, 1)] = j0 + 3;
        __syncthreads();

        const int m = cnt;            // expected ~4 per chunk
        for (int base = 0; base < m; base += 4) {
            const int idx = base + wid;
            if (idx < m) {
                const int j = list[idx];
                accReg += z[j * 64 + lane];   // coalesced 256B per wave, L2-hit
            }
        }
    }

    // Reduce deg across the block
#pragma unroll
    for (int off = 32; off > 0; off >>= 1)
        degLocal += __shfl_down(degLocal, off, 64);
    if (lane == 0) degw[wid] = degLocal;
    accw[wid][lane] = accReg;
    __syncthreads();

    if (t < 64) {
        const float deg = degw[0] + degw[1] + degw[2] + degw[3];
        const float sumNbr = accw[0][t] + accw[1][t] + accw[2][t] + accw[3][t];
        const float e = ev[i], d = dv[i];
        const float S = (deg - 1.f) * e + d;
        const float zif = z[i * 64 + t];
        const float h = zif * (1.f + (e - d) / S) - (e / S) * sumNbr;
        out[(size_t)i * 64 + t] = h > 0.f ? h : 0.f;
    }
}

extern "C" void kernel_launch(void* const* d_in, const int* in_sizes, int n_in,
                              void* d_out, int out_size, void* d_ws, size_t ws_size,
                              hipStream_t stream) {
    const float* X  = (const float*)d_in[0];   // [8192,128]
    const float* A  = (const float*)d_in[1];   // [8192,8192]
    const float* W  = (const float*)d_in[2];   // [64,128]
    const float* b  = (const float*)d_in[3];   // [64]
    const float* a1 = (const float*)d_in[4];   // [64]
    const float* a2 = (const float*)d_in[5];   // [64]
    float* out = (float*)d_out;                // [8192,64]

    float* ws = (float*)d_ws;
    float* z  = ws;                 // 8192*64
    float* ev = ws + NN * OUT_F;    // 8192
    float* dv = ev + NN;            // 8192

    k1_linear<<<NN / 4, 256, 0, stream>>>(X, W, b, a1, a2, z, ev, dv);
    k2_row<<<NN, 256, 0, stream>>>(A, z, ev, dv, out);
}

// Round 2
// 72.119 us; speedup vs baseline: 1.0460x; 1.0460x over previous
//
#include <hip/hip_runtime.h>
#include <math.h>

#define NN 8192
#define IN_F 128
#define OUT_F 64
#define NEG_SLOPE 0.01f
#define K1_ROWS 32   // rows of z per block in k1

// Kernel 1: z = X @ W^T + b ; per-row zi = dot(a1,z_i), zj = dot(a2,z_i);
// e_i = exp(lrelu(zi)), d_i = exp(lrelu(zi+zj)).
// 256 threads = 4 waves; each wave computes 8 rows (lane = output feature).
__global__ __launch_bounds__(256) void k1_linear(
    const float* __restrict__ X, const float* __restrict__ W,
    const float* __restrict__ b, const float* __restrict__ a1,
    const float* __restrict__ a2, float* __restrict__ z,
    float* __restrict__ ev, float* __restrict__ dv)
{
    __shared__ float Wl[OUT_F * 129];        // +1 pad: 2-way conflict only (free)
    __shared__ float xs[K1_ROWS * IN_F];     // 16 KB
    const int t = threadIdx.x;
    const int blk = blockIdx.x;

    // Stage W [64x128] (coalesced)
    for (int idx = t; idx < OUT_F * IN_F; idx += 256) {
        int f = idx >> 7, k = idx & 127;
        Wl[f * 129 + k] = W[idx];
    }
    // Stage 32 rows of X as float4 (coalesced)
    {
        const float4* Xv = reinterpret_cast<const float4*>(X + (size_t)blk * (K1_ROWS * IN_F));
        float4* xsv = reinterpret_cast<float4*>(xs);
#pragma unroll
        for (int idx = t; idx < K1_ROWS * IN_F / 4; idx += 256)
            xsv[idx] = Xv[idx];
    }
    __syncthreads();

    const int wid = t >> 6;
    const int lane = t & 63;    // output feature
    const float bias = b[lane];
    const float a1f = a1[lane], a2f = a2[lane];

#pragma unroll
    for (int r8 = 0; r8 < 8; ++r8) {
        const int row = wid * 8 + r8;          // row within block
        float acc = 0.f;
#pragma unroll 8
        for (int k = 0; k < IN_F; ++k)
            acc = fmaf(xs[row * IN_F + k], Wl[lane * 129 + k], acc);
        const float zval = acc + bias;
        const int i = blk * K1_ROWS + row;
        z[i * OUT_F + lane] = zval;            // coalesced 256B per wave

        float p1 = a1f * zval;
        float p2 = a2f * zval;
#pragma unroll
        for (int off = 32; off > 0; off >>= 1) {
            p1 += __shfl_down(p1, off, 64);
            p2 += __shfl_down(p2, off, 64);
        }
        if (lane == 0) {
            const float s1 = p1;
            const float s2 = p1 + p2;
            const float l1 = s1 > 0.f ? s1 : NEG_SLOPE * s1;
            const float l2 = s2 > 0.f ? s2 : NEG_SLOPE * s2;
            ev[i] = expf(l1);
            dv[i] = expf(l2);
        }
    }
}

// Kernel 2: one block per row i; 4 waves, each owns a contiguous 2048-col
// slice. Barrier-free hot loop: issue all 8 float4 loads, then per-wave
// ballot + bit-scan to gather z[j,:] for nonzero columns. A is exactly 0/1
// but we sum values for deg to stay assumption-light.
//   S = (deg-1)*e + d ;  out = relu( z_i*(1+(e-d)/S) - (e/S)*sumNbr ).
__global__ __launch_bounds__(256) void k2_row(
    const float* __restrict__ A, const float* __restrict__ z,
    const float* __restrict__ ev, const float* __restrict__ dv,
    float* __restrict__ out)
{
    __shared__ float accw[4][64];
    __shared__ float degw[4];

    const int i = blockIdx.x;
    const int t = threadIdx.x;
    const int wid = t >> 6, lane = t & 63;
    const float4* __restrict__ Arow =
        reinterpret_cast<const float4*>(A + (size_t)i * NN);

    // Issue all 8 loads for this wave's 2048-column slice (stay in flight).
    float4 v[8];
#pragma unroll
    for (int c = 0; c < 8; ++c)
        v[c] = Arow[wid * 512 + c * 64 + lane];

    float acc = 0.f;   // partial sumNbr[lane]
    float deg = 0.f;

#pragma unroll
    for (int c = 0; c < 8; ++c) {
        const float4 a4 = v[c];
        deg += a4.x + a4.y + a4.z + a4.w;
        const int jbase = wid * 2048 + c * 256;    // + l*4 + comp
        unsigned long long m;
        m = __ballot(a4.x != 0.f);
        while (m) { int l = __builtin_ctzll(m); m &= m - 1;
                    acc += z[(size_t)(jbase + l * 4 + 0) * OUT_F + lane]; }
        m = __ballot(a4.y != 0.f);
        while (m) { int l = __builtin_ctzll(m); m &= m - 1;
                    acc += z[(size_t)(jbase + l * 4 + 1) * OUT_F + lane]; }
        m = __ballot(a4.z != 0.f);
        while (m) { int l = __builtin_ctzll(m); m &= m - 1;
                    acc += z[(size_t)(jbase + l * 4 + 2) * OUT_F + lane]; }
        m = __ballot(a4.w != 0.f);
        while (m) { int l = __builtin_ctzll(m); m &= m - 1;
                    acc += z[(size_t)(jbase + l * 4 + 3) * OUT_F + lane]; }
    }

    // Reduce deg within wave
#pragma unroll
    for (int off = 32; off > 0; off >>= 1)
        deg += __shfl_down(deg, off, 64);
    if (lane == 0) degw[wid] = deg;
    accw[wid][lane] = acc;
    __syncthreads();

    if (t < 64) {
        const float degT = degw[0] + degw[1] + degw[2] + degw[3];
        const float sumNbr = accw[0][t] + accw[1][t] + accw[2][t] + accw[3][t];
        const float e = ev[i], d = dv[i];
        const float S = (degT - 1.f) * e + d;
        const float zif = z[(size_t)i * OUT_F + t];
        const float h = zif * (1.f + (e - d) / S) - (e / S) * sumNbr;
        out[(size_t)i * OUT_F + t] = h > 0.f ? h : 0.f;
    }
}

extern "C" void kernel_launch(void* const* d_in, const int* in_sizes, int n_in,
                              void* d_out, int out_size, void* d_ws, size_t ws_size,
                              hipStream_t stream) {
    const float* X  = (const float*)d_in[0];   // [8192,128]
    const float* A  = (const float*)d_in[1];   // [8192,8192]
    const float* W  = (const float*)d_in[2];   // [64,128]
    const float* b  = (const float*)d_in[3];   // [64]
    const float* a1 = (const float*)d_in[4];   // [64]
    const float* a2 = (const float*)d_in[5];   // [64]
    float* out = (float*)d_out;                // [8192,64]

    float* ws = (float*)d_ws;
    float* z  = ws;                 // 8192*64
    float* ev = ws + NN * OUT_F;    // 8192
    float* dv = ev + NN;            // 8192

    k1_linear<<<NN / K1_ROWS, 256, 0, stream>>>(X, W, b, a1, a2, z, ev, dv);
    k2_row<<<NN, 256, 0, stream>>>(A, z, ev, dv, out);
}

// Round 3
// 67.363 us; speedup vs baseline: 1.1198x; 1.0706x over previous
//
#include <hip/hip_runtime.h>
#include <math.h>

#define NN 8192
#define IN_F 128
#define OUT_F 64
#define NEG_SLOPE 0.01f
#define K1_ROWS 8    // rows of z per block in k1 -> 1024 blocks, 4/CU

// Kernel 1: z = X @ W^T + b ; per-row zi = dot(a1,z_i), zj = dot(a2,z_i);
// e_i = exp(lrelu(zi)), d_i = exp(lrelu(zi+zj)).
// 256 threads = 4 waves; each wave computes 2 rows (lane = output feature).
__global__ __launch_bounds__(256, 4) void k1_linear(
    const float* __restrict__ X, const float* __restrict__ W,
    const float* __restrict__ b, const float* __restrict__ a1,
    const float* __restrict__ a2, float* __restrict__ z,
    float* __restrict__ ev, float* __restrict__ dv)
{
    __shared__ float Wl[OUT_F * 129];        // 33 KB; stride 129 -> conflict-free
    __shared__ float xs[K1_ROWS * IN_F];     // 4 KB
    const int t = threadIdx.x;
    const int blk = blockIdx.x;

    // Stage W [64x128] (coalesced, L2-hot after first block)
    for (int idx = t; idx < OUT_F * IN_F; idx += 256) {
        int f = idx >> 7, k = idx & 127;
        Wl[f * 129 + k] = W[idx];
    }
    // Stage 8 rows of X as float4 (coalesced)
    {
        const float4* Xv = reinterpret_cast<const float4*>(X + (size_t)blk * (K1_ROWS * IN_F));
        float4* xsv = reinterpret_cast<float4*>(xs);
        if (t < K1_ROWS * IN_F / 4) xsv[t] = Xv[t];
    }
    __syncthreads();

    const int wid = t >> 6;
    const int lane = t & 63;    // output feature
    const float bias = b[lane];
    const float a1f = a1[lane], a2f = a2[lane];

#pragma unroll
    for (int r2 = 0; r2 < 2; ++r2) {
        const int row = wid * 2 + r2;          // row within block
        float acc = 0.f;
#pragma unroll 8
        for (int k = 0; k < IN_F; ++k)
            acc = fmaf(xs[row * IN_F + k], Wl[lane * 129 + k], acc);
        const float zval = acc + bias;
        const int i = blk * K1_ROWS + row;
        z[i * OUT_F + lane] = zval;            // coalesced 256B per wave

        float p1 = a1f * zval;
        float p2 = a2f * zval;
#pragma unroll
        for (int off = 32; off > 0; off >>= 1) {
            p1 += __shfl_down(p1, off, 64);
            p2 += __shfl_down(p2, off, 64);
        }
        if (lane == 0) {
            const float s1 = p1;
            const float s2 = p1 + p2;
            const float l1 = s1 > 0.f ? s1 : NEG_SLOPE * s1;
            const float l2 = s2 > 0.f ? s2 : NEG_SLOPE * s2;
            ev[i] = expf(l1);
            dv[i] = expf(l2);
        }
    }
}

// Kernel 2: one block per row i; 4 waves, each owns a contiguous 2048-col
// slice. Phase 1: stream 8 float4 loads -> packed 32-bit nonzero mask per
// lane (pure VALU consumption, no vmcnt drains mid-stream). deg = popcount.
// Phase 2: ballot from packed bits, wave-cooperative gather of z[j,:],
// 2-wide unrolled to shorten the dependent-load chain.
//   S = (deg-1)*e + d ;  out = relu( z_i*(1+(e-d)/S) - (e/S)*sumNbr ).
__global__ __launch_bounds__(256, 6) void k2_row(
    const float* __restrict__ A, const float* __restrict__ z,
    const float* __restrict__ ev, const float* __restrict__ dv,
    float* __restrict__ out)
{
    __shared__ float accw[4][64];
    __shared__ int   degw[4];

    const int i = blockIdx.x;
    const int t = threadIdx.x;
    const int wid = t >> 6, lane = t & 63;
    const float4* __restrict__ Arow =
        reinterpret_cast<const float4*>(A + (size_t)i * NN);

    // Issue all 8 loads for this wave's 2048-column slice.
    float4 v[8];
#pragma unroll
    for (int c = 0; c < 8; ++c)
        v[c] = Arow[wid * 512 + c * 64 + lane];

    // Phase 1: pack nonzero flags; loads retire in order (vmcnt(7-c)).
    unsigned int bits = 0;
#pragma unroll
    for (int c = 0; c < 8; ++c) {
        bits |= (v[c].x != 0.f ? 1u : 0u) << (c * 4 + 0);
        bits |= (v[c].y != 0.f ? 1u : 0u) << (c * 4 + 1);
        bits |= (v[c].z != 0.f ? 1u : 0u) << (c * 4 + 2);
        bits |= (v[c].w != 0.f ? 1u : 0u) << (c * 4 + 3);
    }
    int deg = __popc(bits);   // A is exactly {0,1} (reduction already relies on it)

    // Phase 2: gather. A-stream is fully retired; only z loads outstanding.
    float acc = 0.f;   // partial sumNbr[lane]
#pragma unroll
    for (int c = 0; c < 8; ++c) {
#pragma unroll
        for (int k = 0; k < 4; ++k) {
            unsigned long long m = __ballot(((bits >> (c * 4 + k)) & 1u) != 0u);
            const int jbase = wid * 2048 + c * 256 + k;   // + l*4
            while (m) {
                const int l0 = __builtin_ctzll(m); m &= m - 1;
                if (m) {
                    const int l1 = __builtin_ctzll(m); m &= m - 1;
                    const float z0 = z[(size_t)(jbase + l0 * 4) * OUT_F + lane];
                    const float z1 = z[(size_t)(jbase + l1 * 4) * OUT_F + lane];
                    acc += z0 + z1;
                } else {
                    acc += z[(size_t)(jbase + l0 * 4) * OUT_F + lane];
                }
            }
        }
    }

    // Reduce deg within wave
#pragma unroll
    for (int off = 32; off > 0; off >>= 1)
        deg += __shfl_down(deg, off, 64);
    if (lane == 0) degw[wid] = deg;
    accw[wid][lane] = acc;
    __syncthreads();

    if (t < 64) {
        const float degT = (float)(degw[0] + degw[1] + degw[2] + degw[3]);
        const float sumNbr = accw[0][t] + accw[1][t] + accw[2][t] + accw[3][t];
        const float e = ev[i], d = dv[i];
        const float S = (degT - 1.f) * e + d;
        const float zif = z[(size_t)i * OUT_F + t];
        const float h = zif * (1.f + (e - d) / S) - (e / S) * sumNbr;
        out[(size_t)i * OUT_F + t] = h > 0.f ? h : 0.f;
    }
}

extern "C" void kernel_launch(void* const* d_in, const int* in_sizes, int n_in,
                              void* d_out, int out_size, void* d_ws, size_t ws_size,
                              hipStream_t stream) {
    const float* X  = (const float*)d_in[0];   // [8192,128]
    const float* A  = (const float*)d_in[1];   // [8192,8192]
    const float* W  = (const float*)d_in[2];   // [64,128]
    const float* b  = (const float*)d_in[3];   // [64]
    const float* a1 = (const float*)d_in[4];   // [64]
    const float* a2 = (const float*)d_in[5];   // [64]
    float* out = (float*)d_out;                // [8192,64]

    float* ws = (float*)d_ws;
    float* z  = ws;                 // 8192*64
    float* ev = ws + NN * OUT_F;    // 8192
    float* dv = ev + NN;            // 8192

    k1_linear<<<NN / K1_ROWS, 256, 0, stream>>>(X, W, b, a1, a2, z, ev, dv);
    k2_row<<<NN, 256, 0, stream>>>(A, z, ev, dv, out);
}

// Round 4
// 67.349 us; speedup vs baseline: 1.1201x; 1.0002x over previous
//
#include <hip/hip_runtime.h>
#include <math.h>

#define NN 8192
#define IN_F 128
#define OUT_F 64
#define NEG_SLOPE 0.01f
#define K1_ROWS 8    // rows of z per block in k1 -> 1024 blocks

// Kernel 1: z = X @ W^T + b ; per-row zi = dot(a1,z_i), zj = dot(a2,z_i);
// e_i = exp(lrelu(zi)), d_i = exp(lrelu(zi+zj)).
__global__ __launch_bounds__(256, 4) void k1_linear(
    const float* __restrict__ X, const float* __restrict__ W,
    const float* __restrict__ b, const float* __restrict__ a1,
    const float* __restrict__ a2, float* __restrict__ z,
    float* __restrict__ ev, float* __restrict__ dv)
{
    __shared__ float Wl[OUT_F * 129];        // stride 129 -> conflict-free
    __shared__ float xs[K1_ROWS * IN_F];
    const int t = threadIdx.x;
    const int blk = blockIdx.x;

    for (int idx = t; idx < OUT_F * IN_F; idx += 256) {
        int f = idx >> 7, k = idx & 127;
        Wl[f * 129 + k] = W[idx];
    }
    {
        const float4* Xv = reinterpret_cast<const float4*>(X + (size_t)blk * (K1_ROWS * IN_F));
        float4* xsv = reinterpret_cast<float4*>(xs);
        if (t < K1_ROWS * IN_F / 4) xsv[t] = Xv[t];
    }
    __syncthreads();

    const int wid = t >> 6;
    const int lane = t & 63;    // output feature
    const float bias = b[lane];
    const float a1f = a1[lane], a2f = a2[lane];

#pragma unroll
    for (int r2 = 0; r2 < 2; ++r2) {
        const int row = wid * 2 + r2;
        float acc = 0.f;
#pragma unroll 8
        for (int k = 0; k < IN_F; ++k)
            acc = fmaf(xs[row * IN_F + k], Wl[lane * 129 + k], acc);
        const float zval = acc + bias;
        const int i = blk * K1_ROWS + row;
        z[i * OUT_F + lane] = zval;

        float p1 = a1f * zval;
        float p2 = a2f * zval;
#pragma unroll
        for (int off = 32; off > 0; off >>= 1) {
            p1 += __shfl_down(p1, off, 64);
            p2 += __shfl_down(p2, off, 64);
        }
        if (lane == 0) {
            const float s1 = p1;
            const float s2 = p1 + p2;
            const float l1 = s1 > 0.f ? s1 : NEG_SLOPE * s1;
            const float l2 = s2 > 0.f ? s2 : NEG_SLOPE * s2;
            ev[i] = expf(l1);
            dv[i] = expf(l2);
        }
    }
}

// Kernel 2: one block per row i; 4 waves, each owns a 2048-col slice.
// Phase 1: stream 8 int4 loads; per chunk an integer or-tree + ONE ballot
// marks float4s with any nonzero (~6 VALU / 256 cols).
// Phase 2: per hit float4 (rare, ~33/row), shuffle its 4 values from the hit
// lane and fmaf into the accumulator unconditionally (A is {0,1}-valued, so
// zero comps contribute nothing; exact). deg accumulates the same shuffled
// values -> wave-uniform, no reduction needed.
//   S = (deg-1)*e + d ;  out = relu( z_i*(1+(e-d)/S) - (e/S)*sumNbr ).
__global__ __launch_bounds__(256, 6) void k2_row(
    const float* __restrict__ A, const float* __restrict__ z,
    const float* __restrict__ ev, const float* __restrict__ dv,
    float* __restrict__ out)
{
    __shared__ float accw[4][64];
    __shared__ float degw[4];

    const int i = blockIdx.x;
    const int t = threadIdx.x;
    const int wid = t >> 6, lane = t & 63;
    const int4* __restrict__ Arow =
        reinterpret_cast<const int4*>(A + (size_t)i * NN);

    // Issue all 8 loads for this wave's 2048-column slice.
    int4 w0 = Arow[wid * 512 + 0 * 64 + lane];
    int4 w1 = Arow[wid * 512 + 1 * 64 + lane];
    int4 w2 = Arow[wid * 512 + 2 * 64 + lane];
    int4 w3 = Arow[wid * 512 + 3 * 64 + lane];
    int4 w4 = Arow[wid * 512 + 4 * 64 + lane];
    int4 w5 = Arow[wid * 512 + 5 * 64 + lane];
    int4 w6 = Arow[wid * 512 + 6 * 64 + lane];
    int4 w7 = Arow[wid * 512 + 7 * 64 + lane];

    // Phase 1: one ballot per chunk (progressive vmcnt, no drains).
    unsigned long long msk[8];
    msk[0] = __ballot(((w0.x | w0.y) | (w0.z | w0.w)) != 0);
    msk[1] = __ballot(((w1.x | w1.y) | (w1.z | w1.w)) != 0);
    msk[2] = __ballot(((w2.x | w2.y) | (w2.z | w2.w)) != 0);
    msk[3] = __ballot(((w3.x | w3.y) | (w3.z | w3.w)) != 0);
    msk[4] = __ballot(((w4.x | w4.y) | (w4.z | w4.w)) != 0);
    msk[5] = __ballot(((w5.x | w5.y) | (w5.z | w5.w)) != 0);
    msk[6] = __ballot(((w6.x | w6.y) | (w6.z | w6.w)) != 0);
    msk[7] = __ballot(((w7.x | w7.y) | (w7.z | w7.w)) != 0);

    float acc = 0.f;   // partial sumNbr[lane]
    float deg = 0.f;   // wave-uniform

#define GATHER_CHUNK(C, W)                                                   \
    {                                                                        \
        unsigned long long m = msk[C];                                       \
        const int jb = wid * 2048 + (C) * 256;                               \
        while (m) {                                                          \
            const int l = __builtin_ctzll(m); m &= m - 1;                    \
            const float vx = __shfl(__int_as_float(W.x), l, 64);             \
            const float vy = __shfl(__int_as_float(W.y), l, 64);             \
            const float vz = __shfl(__int_as_float(W.z), l, 64);             \
            const float vw = __shfl(__int_as_float(W.w), l, 64);             \
            const float* zp = z + (size_t)(jb + l * 4) * OUT_F + lane;       \
            acc = fmaf(vx, zp[0 * OUT_F], acc);                              \
            acc = fmaf(vy, zp[1 * OUT_F], acc);                              \
            acc = fmaf(vz, zp[2 * OUT_F], acc);                              \
            acc = fmaf(vw, zp[3 * OUT_F], acc);                              \
            deg += (vx + vy) + (vz + vw);                                    \
        }                                                                    \
    }

    GATHER_CHUNK(0, w0)
    GATHER_CHUNK(1, w1)
    GATHER_CHUNK(2, w2)
    GATHER_CHUNK(3, w3)
    GATHER_CHUNK(4, w4)
    GATHER_CHUNK(5, w5)
    GATHER_CHUNK(6, w6)
    GATHER_CHUNK(7, w7)
#undef GATHER_CHUNK

    if (lane == 0) degw[wid] = deg;
    accw[wid][lane] = acc;
    __syncthreads();

    if (t < 64) {
        const float degT = degw[0] + degw[1] + degw[2] + degw[3];
        const float sumNbr = accw[0][t] + accw[1][t] + accw[2][t] + accw[3][t];
        const float e = ev[i], d = dv[i];
        const float S = (degT - 1.f) * e + d;
        const float zif = z[(size_t)i * OUT_F + t];
        const float h = zif * (1.f + (e - d) / S) - (e / S) * sumNbr;
        out[(size_t)i * OUT_F + t] = h > 0.f ? h : 0.f;
    }
}

extern "C" void kernel_launch(void* const* d_in, const int* in_sizes, int n_in,
                              void* d_out, int out_size, void* d_ws, size_t ws_size,
                              hipStream_t stream) {
    const float* X  = (const float*)d_in[0];   // [8192,128]
    const float* A  = (const float*)d_in[1];   // [8192,8192]
    const float* W  = (const float*)d_in[2];   // [64,128]
    const float* b  = (const float*)d_in[3];   // [64]
    const float* a1 = (const float*)d_in[4];   // [64]
    const float* a2 = (const float*)d_in[5];   // [64]
    float* out = (float*)d_out;                // [8192,64]

    float* ws = (float*)d_ws;
    float* z  = ws;                 // 8192*64
    float* ev = ws + NN * OUT_F;    // 8192
    float* dv = ev + NN;            // 8192

    k1_linear<<<NN / K1_ROWS, 256, 0, stream>>>(X, W, b, a1, a2, z, ev, dv);
    k2_row<<<NN, 256, 0, stream>>>(A, z, ev, dv, out);
}